// Round 8
// baseline (212.651 us; speedup 1.0000x reference)
//
#include <hip/hip_runtime.h>

#define B_SZ 4
#define SEQ  2048
#define CH   768
#define NH   12
#define HD   64

typedef float f32x4  __attribute__((ext_vector_type(4)));
typedef __bf16 bf16x8 __attribute__((ext_vector_type(8)));
typedef __bf16 bf16x2 __attribute__((ext_vector_type(2)));

#define MFMA16(a,b,c) __builtin_amdgcn_mfma_f32_16x16x32_bf16(a,b,c,0,0,0)

// scale = 1/sqrt(64) * log2(e)  -> softmax uses exp2
#define QSCALE 0.1803368801111204f

#if __has_builtin(__builtin_amdgcn_exp2f)
#define EXP2(x) __builtin_amdgcn_exp2f(x)
#else
#define EXP2(x) exp2f(x)
#endif

// flash LDS swizzle
#define SWZ(row) (((row) ^ ((row) >> 3)) & 7)

__device__ __forceinline__ unsigned pack2(float a, float b) {
    union { bf16x2 v; unsigned u; } p;
    p.v[0] = (__bf16)a; p.v[1] = (__bf16)b;
    return p.u;
}

// async global->LDS, 16B per lane. lds dest must be wave-uniform base + lane*16.
__device__ __forceinline__ void lds_dma16(const void* g, void* l) {
    __builtin_amdgcn_global_load_lds(
        (const __attribute__((address_space(1))) void*)g,
        (__attribute__((address_space(3))) void*)(unsigned)(unsigned long long)l,
        16, 0, 0);
}

// ---------------- fused fp32 -> bf16 convert (x | qkv_w | proj_w in one launch) ------------
#define NBLK_X  6144   // 6291456 / 1024
#define NBLK_W  1728   // 1769472 / 1024
#define NBLK_P   576   //  589824 / 1024
__global__ __launch_bounds__(256) void convert_all(const float* __restrict__ x,
                                                   const float* __restrict__ w,
                                                   const float* __restrict__ p,
                                                   __bf16* __restrict__ ox,
                                                   __bf16* __restrict__ ow,
                                                   __bf16* __restrict__ op) {
    int blk = blockIdx.x;
    const float* src;
    __bf16* dst;
    int base;
    if (blk < NBLK_X)               { src = x; dst = ox; base = blk; }
    else if (blk < NBLK_X + NBLK_W) { src = w; dst = ow; base = blk - NBLK_X; }
    else                            { src = p; dst = op; base = blk - NBLK_X - NBLK_W; }
    int i = (base * 256 + threadIdx.x) * 4;
    float4 v = *(const float4*)(src + i);
    union { __bf16 h[4]; uint2 u; } o;
    o.h[0] = (__bf16)v.x; o.h[1] = (__bf16)v.y; o.h[2] = (__bf16)v.z; o.h[3] = (__bf16)v.w;
    *(uint2*)(dst + i) = o.u;
}

// ---------------- 128x128 tile (BK=64) MFMA mainloop: C = A(MxK) * B(NxK)^T ----------------
// LDS layout: row-major [128][64] bf16, 16B chunk c stored at phys chunk c ^ (row&7).
__device__ __forceinline__ void gemm128_loop(const __bf16* __restrict__ A,
                                             const __bf16* __restrict__ Bm,
                                             int K, int rowBlk, int colBlk,
                                             __bf16* As, __bf16* Bs,
                                             f32x4 acc[4][4]) {
    const int tid  = threadIdx.x;
    const int lane = tid & 63, wid = tid >> 6;
    const int quad = lane >> 4, l16 = lane & 15;
    const int wm = wid >> 1, wn = wid & 1;

    f32x4 z = {0.f, 0.f, 0.f, 0.f};
#pragma unroll
    for (int mi = 0; mi < 4; ++mi)
#pragma unroll
        for (int ni = 0; ni < 4; ++ni) acc[mi][ni] = z;

    for (int k0 = 0; k0 < K; k0 += 64) {
        __syncthreads();
#pragma unroll
        for (int i = 0; i < 4; ++i) {
            int s = i * 256 + tid;
            int row = s >> 3, pc = s & 7;
            int lc = pc ^ (row & 7);
            lds_dma16(A  + (size_t)(rowBlk + row) * K + k0 + lc * 8, As + s * 8);
            lds_dma16(Bm + (size_t)(colBlk + row) * K + k0 + lc * 8, Bs + s * 8);
        }
        __syncthreads();

#pragma unroll
        for (int kc = 0; kc < 2; ++kc) {
            bf16x8 af[4], bfr[4];
#pragma unroll
            for (int mi = 0; mi < 4; ++mi) {
                int row = wm * 64 + mi * 16 + l16;
                int pc = (quad + 4 * kc) ^ (row & 7);
                af[mi] = *(const bf16x8*)(As + row * 64 + pc * 8);
            }
#pragma unroll
            for (int ni = 0; ni < 4; ++ni) {
                int row = wn * 64 + ni * 16 + l16;
                int pc = (quad + 4 * kc) ^ (row & 7);
                bfr[ni] = *(const bf16x8*)(Bs + row * 64 + pc * 8);
            }
#pragma unroll
            for (int mi = 0; mi < 4; ++mi)
#pragma unroll
                for (int ni = 0; ni < 4; ++ni)
                    acc[mi][ni] = MFMA16(af[mi], bfr[ni], acc[mi][ni]);
        }
    }
}

// ---------------- QKV GEMM: X(8192x768) @ Wqkv(2304x768)^T, scatter to Q/K/Vt ----------------
// R8: XCD-chunked 1D grid. Default (64,18) x-fastest dispatch gives each XCD's ~144 concurrent
// blocks ALL 64 A-row-panels (12.6MB >> 4MB L2) -> A thrash, ~18x re-reads from L3 (~227MB).
// Remap: XCD k owns row-blocks [8k,8k+8) x all 18 col-blocks (col fastest) -> per-XCD working
// set = A 1.57MB + B 3.5MB ~= L2-resident. Q/K epilogue keeps R7's LDS-transposed uint4 stores.
__global__ __launch_bounds__(256) void qkv_gemm(const __bf16* __restrict__ Xb,
                                                const __bf16* __restrict__ Wb,
                                                __bf16* __restrict__ Qb,
                                                __bf16* __restrict__ Kb,
                                                __bf16* __restrict__ Vt) {
    __shared__ __bf16 smem[128 * 128];   // 32 KB: mainloop uses first 16 KB; epilogue all
    f32x4 acc[4][4];
    const int lin = blockIdx.x;              // 0..1151
    const int xcd = lin & 7, idx = lin >> 3; // idx 0..143
    const int colB = idx % 18;               // col-block, fastest within XCD chunk
    const int rowB = xcd * 8 + idx / 18;     // row-block 0..63
    const int rowBlk = rowB * 128, colBlk = colB * 128;
    gemm128_loop(Xb, Wb, CH, rowBlk, colBlk, smem, smem + 128 * 64, acc);

    const int tid = threadIdx.x;
    const int lane = tid & 63, wid = tid >> 6;
    const int quad = lane >> 4, l16 = lane & 15, wm = wid >> 1, wn = wid & 1;
    const int b = rowBlk >> 11, n0 = rowBlk & (SEQ - 1);

    if (colBlk < 2 * CH) {
        const int isK = (colBlk >= CH);
        const float sc = isK ? 1.f : QSCALE;
        const int hb = (colBlk - (isK ? CH : 0)) >> 6;   // base head of this 128-col block
        __syncthreads();   // mainloop LDS readers done; reuse as [128][128]
#pragma unroll
        for (int mi = 0; mi < 4; ++mi)
#pragma unroll
            for (int ni = 0; ni < 4; ++ni)
#pragma unroll
                for (int r = 0; r < 4; ++r) {
                    int rl = wm * 64 + mi * 16 + quad * 4 + r;   // n-local
                    int cl = wn * 64 + ni * 16 + l16;            // col-local (2 heads x 64 d)
                    smem[rl * 128 + (cl ^ ((rl & 15) << 3))] = (__bf16)(acc[mi][ni][r] * sc);
                }
        __syncthreads();
        __bf16* dst0 = isK ? Kb : Qb;
        const int rbase = tid >> 4;          // 0..15
        const int c = (tid & 15) * 8;        // 0..120, 8-aligned
        const int h = hb + (c >> 6), d = c & 63;
#pragma unroll
        for (int j = 0; j < 8; ++j) {
            int rl = j * 16 + rbase;
            uint4 val = *(const uint4*)(smem + rl * 128 + (c ^ ((rl & 15) << 3)));
            *(uint4*)(dst0 + (size_t)((b * NH + h) * SEQ + n0 + rl) * HD + d) = val;
        }
    } else {
        // V: transpose through LDS, write V^T coalesced
        const int vblk = colBlk - 2 * CH;
        __syncthreads();
#pragma unroll
        for (int mi = 0; mi < 4; ++mi)
#pragma unroll
            for (int ni = 0; ni < 4; ++ni)
#pragma unroll
                for (int r = 0; r < 4; ++r) {
                    int rl = wm * 64 + mi * 16 + quad * 4 + r;   // n-local
                    int cl = wn * 64 + ni * 16 + l16;            // d-local
                    smem[cl * 128 + (((rl >> 3) ^ (cl & 15)) << 3) + (rl & 7)] =
                        (__bf16)acc[mi][ni][r];
                }
        __syncthreads();
        const int dl = tid >> 1;
        const int d  = vblk + dl;
        const int h  = d >> 6, dd = d & 63;
        const size_t base = (size_t)((b * NH + h) * HD + dd) * SEQ + n0;
#pragma unroll
        for (int j2 = 0; j2 < 8; ++j2) {
            int j = (tid & 1) * 8 + j2;
            uint4 val = *(const uint4*)(smem + dl * 128 + ((j ^ (dl & 15)) << 3));
            *(uint4*)(Vt + base + j * 8) = val;
        }
    }
}

// ---------------- Flash attention v9 (proven ~68us, byte-identical to R0/R7) -----------------
__global__ __launch_bounds__(256, 3) void flash_attn(const __bf16* __restrict__ Qb,
                                                     const __bf16* __restrict__ Kb,
                                                     const __bf16* __restrict__ Vt,
                                                     __bf16* __restrict__ Ab) {
    __shared__ __bf16 smem[16384];       // 32 KB: Ks0|Vs0|Ks1|Vs1 (4KB elements each)
                                         // epilogue reuses first 18 KB as [128][72]

    const int tid  = threadIdx.x;
    const int lane = tid & 63, wid = tid >> 6;
    const int quad = lane >> 4, l16 = lane & 15;

    // XCD-aware decode: blk%8 = XCD; 6 bh x 16 qblk per XCD.
    const int lin  = blockIdx.x;              // 0..767
    const int xcd  = lin & 7, idx = lin >> 3; // idx 0..95
    const int bh   = xcd * 6 + (idx >> 4);    // 0..47
    const int qblk = idx & 15;                // 0..15 (128 queries each)
    const int b    = bh / NH, head = bh - b * NH;

    const int qA = qblk * 128 + wid * 16 + l16;
    const int qB = qA + 64;

    // Q^T B-frags (held whole kernel): lane n=l16=q, k(d) = kcd*32 + quad*8 + j
    bf16x8 qfA[2], qfB[2];
#pragma unroll
    for (int kcd = 0; kcd < 2; ++kcd) {
        qfA[kcd] = *(const bf16x8*)(Qb + (size_t)(bh * SEQ + qA) * HD + kcd * 32 + quad * 8);
        qfB[kcd] = *(const bf16x8*)(Qb + (size_t)(bh * SEQ + qB) * HD + kcd * 32 + quad * 8);
    }

    // key permutation (even/odd groups) for zero-cndmask P exchange
    const int key_e = ((l16 >> 2) << 3) + (l16 & 3);
    const int key_o = ((((l16 >> 2) ^ 1)) << 3) + 4 + (l16 & 3);

    f32x4 otA[4], otB[4];
    f32x4 z = {0.f, 0.f, 0.f, 0.f};
#pragma unroll
    for (int dg = 0; dg < 4; ++dg) { otA[dg] = z; otB[dg] = z; }
    float lA = 0.f, lB = 0.f;

    const __bf16* Kbh = Kb + (size_t)bh * SEQ * HD;
    const __bf16* Vbh = Vt + (size_t)bh * HD * SEQ;

    const int s_row = tid >> 3, s_pc = tid & 7;
    const int s_lc0 = s_pc ^ SWZ(s_row);
    const int s_lc1 = s_pc ^ SWZ(s_row + 32);

// proven R8 64-key body on sub-tile at (Ks, Vs)
#define PROCESS(Ks, Vs)                                                                       \
    do {                                                                                      \
        f32x4 stA[4], stB[4];                                                                 \
        _Pragma("unroll")                                                                     \
        for (int g = 0; g < 4; ++g) { stA[g] = z; stB[g] = z; }                               \
        _Pragma("unroll")                                                                     \
        for (int g = 0; g < 4; ++g) {                                                         \
            const int key = ((g >> 1) << 5) + ((g & 1) ? key_o : key_e);                      \
            _Pragma("unroll")                                                                 \
            for (int kcd = 0; kcd < 2; ++kcd) {                                               \
                int c8 = quad + (kcd << 2);                                                   \
                bf16x8 kf = *(const bf16x8*)((Ks) + key * 64 + ((c8 ^ SWZ(key)) << 3));       \
                stA[g] = MFMA16(kf, qfA[kcd], stA[g]);                                        \
                stB[g] = MFMA16(kf, qfB[kcd], stB[g]);                                        \
            }                                                                                 \
        }                                                                                     \
        bf16x8 pfA[2], pfB[2];                                                                \
        _Pragma("unroll")                                                                     \
        for (int g = 0; g < 4; ++g)                                                           \
            _Pragma("unroll")                                                                 \
            for (int r = 0; r < 4; ++r) {                                                     \
                float p = EXP2(stA[g][r]);                                                    \
                stA[g][r] = p;                                                                \
                lA += p;                                                                      \
            }                                                                                 \
        _Pragma("unroll")                                                                     \
        for (int kk = 0; kk < 2; ++kk) {                                                      \
            unsigned w0 = pack2(stA[2 * kk][0], stA[2 * kk][1]);                              \
            unsigned w1 = pack2(stA[2 * kk][2], stA[2 * kk][3]);                              \
            unsigned x0 = pack2(stA[2 * kk + 1][0], stA[2 * kk + 1][1]);                      \
            unsigned x1 = pack2(stA[2 * kk + 1][2], stA[2 * kk + 1][3]);                      \
            unsigned w2 = (unsigned)__shfl_xor((int)x0, 16, 64);                              \
            unsigned w3 = (unsigned)__shfl_xor((int)x1, 16, 64);                              \
            union { bf16x8 v; unsigned u[4]; } f;                                             \
            f.u[0] = w0; f.u[1] = w1; f.u[2] = w2; f.u[3] = w3;                               \
            pfA[kk] = f.v;                                                                    \
        }                                                                                     \
        _Pragma("unroll")                                                                     \
        for (int g = 0; g < 4; ++g)                                                           \
            _Pragma("unroll")                                                                 \
            for (int r = 0; r < 4; ++r) {                                                     \
                float p = EXP2(stB[g][r]);                                                    \
                stB[g][r] = p;                                                                \
                lB += p;                                                                      \
            }                                                                                 \
        _Pragma("unroll")                                                                     \
        for (int kk = 0; kk < 2; ++kk) {                                                      \
            unsigned w0 = pack2(stB[2 * kk][0], stB[2 * kk][1]);                              \
            unsigned w1 = pack2(stB[2 * kk][2], stB[2 * kk][3]);                              \
            unsigned x0 = pack2(stB[2 * kk + 1][0], stB[2 * kk + 1][1]);                      \
            unsigned x1 = pack2(stB[2 * kk + 1][2], stB[2 * kk + 1][3]);                      \
            unsigned w2 = (unsigned)__shfl_xor((int)x0, 16, 64);                              \
            unsigned w3 = (unsigned)__shfl_xor((int)x1, 16, 64);                              \
            union { bf16x8 v; unsigned u[4]; } f;                                             \
            f.u[0] = w0; f.u[1] = w1; f.u[2] = w2; f.u[3] = w3;                               \
            pfB[kk] = f.v;                                                                    \
        }                                                                                    \
        _Pragma("unroll")                                                                     \
        for (int dg = 0; dg < 4; ++dg)                                                        \
            _Pragma("unroll")                                                                 \
            for (int kk = 0; kk < 2; ++kk) {                                                  \
                int row = (dg << 4) + l16;                                                    \
                int c8 = quad + (kk << 2);                                                    \
                bf16x8 vf = *(const bf16x8*)((Vs) + row * 64 + ((c8 ^ SWZ(row)) << 3));       \
                otA[dg] = MFMA16(vf, pfA[kk], otA[dg]);                                       \
                otB[dg] = MFMA16(vf, pfB[kk], otB[dg]);                                       \
            }                                                                                 \
    } while (0)

    for (int kb = 0; kb < SEQ / 128; ++kb) {
        const int kbase = kb * 128;
        __syncthreads();   // prior-iteration LDS readers done
        // sub-tile 0: keys kbase..kbase+63
        lds_dma16(Kbh + (size_t)(kbase + s_row) * HD + s_lc0 * 8,            smem + tid * 8);
        lds_dma16(Kbh + (size_t)(kbase + s_row + 32) * HD + s_lc1 * 8,       smem + 2048 + tid * 8);
        lds_dma16(Vbh + (size_t)s_row * SEQ + kbase + s_lc0 * 8,             smem + 4096 + tid * 8);
        lds_dma16(Vbh + (size_t)(s_row + 32) * SEQ + kbase + s_lc1 * 8,      smem + 6144 + tid * 8);
        // sub-tile 1: keys kbase+64..kbase+127
        lds_dma16(Kbh + (size_t)(kbase + 64 + s_row) * HD + s_lc0 * 8,       smem + 8192 + tid * 8);
        lds_dma16(Kbh + (size_t)(kbase + 96 + s_row) * HD + s_lc1 * 8,       smem + 10240 + tid * 8);
        lds_dma16(Vbh + (size_t)s_row * SEQ + kbase + 64 + s_lc0 * 8,        smem + 12288 + tid * 8);
        lds_dma16(Vbh + (size_t)(s_row + 32) * SEQ + kbase + 64 + s_lc1 * 8, smem + 14336 + tid * 8);
        __syncthreads();   // drains dma

        PROCESS(smem, smem + 4096);
        PROCESS(smem + 8192, smem + 12288);
    }
#undef PROCESS

    lA += __shfl_xor(lA, 16, 64);
    lA += __shfl_xor(lA, 32, 64);
    lB += __shfl_xor(lB, 16, 64);
    lB += __shfl_xor(lB, 32, 64);
    const float rA = 1.f / lA, rB = 1.f / lB;

    __syncthreads();   // reuse smem as [128][72] for O transpose
    __bf16 (*Ob)[72] = (__bf16(*)[72])smem;
#pragma unroll
    for (int dg = 0; dg < 4; ++dg)
#pragma unroll
        for (int r = 0; r < 4; ++r) {
            int d = (dg << 4) + (quad << 2) + r;
            Ob[wid * 16 + l16][d]      = (__bf16)(otA[dg][r] * rA);
            Ob[64 + wid * 16 + l16][d] = (__bf16)(otB[dg][r] * rB);
        }
    __syncthreads();
    {
        const int row = tid >> 1, c0 = (tid & 1) * 32;
        __bf16* dst = Ab + (size_t)(b * SEQ + qblk * 128 + row) * CH + head * HD + c0;
#pragma unroll
        for (int j = 0; j < 4; ++j)
            *(uint4*)(dst + j * 8) = *(const uint4*)(&Ob[row][c0 + j * 8]);
    }
}

// ---------------- Projection GEMM: Attn(8192x768) @ proj_w(768x768)^T + bias ----------------
// R8: XCD-chunked grid (8 rows x 6 cols per XCD -> working set 2.8MB, L2-fit) + vectorized
// f32 epilogue: two 64-row halves staged to LDS [64][132] f32 (pad kills pow2 banks; 2-way
// write alias only), stored as f32x4 at full 512B/row coalescing; bias fused at staging.
__global__ __launch_bounds__(256) void proj_gemm(const __bf16* __restrict__ Ab,
                                                 const __bf16* __restrict__ Pw,
                                                 const float* __restrict__ bias,
                                                 float* __restrict__ out) {
    __shared__ __align__(16) char pSmem[64 * 132 * 4];   // 33792 B >= As+Bs (32768)
    __bf16* As = (__bf16*)pSmem;
    __bf16* Bs = As + 128 * 64;
    float*  Ep = (float*)pSmem;                          // [64][132] f32 epilogue buffer

    f32x4 acc[4][4];
    const int lin = blockIdx.x;              // 0..383
    const int xcd = lin & 7, idx = lin >> 3; // idx 0..47
    const int colB = idx % 6;
    const int rowB = xcd * 8 + idx / 6;      // 0..63
    const int rowBlk = rowB * 128, colBlk = colB * 128;
    gemm128_loop(Ab, Pw, CH, rowBlk, colBlk, As, Bs, acc);

    const int tid  = threadIdx.x;
    const int lane = tid & 63, wid = tid >> 6;
    const int quad = lane >> 4, l16 = lane & 15, wm = wid >> 1, wn = wid & 1;

    __syncthreads();   // mainloop LDS readers done
#pragma unroll
    for (int h = 0; h < 2; ++h) {
        if (wm == h) {
#pragma unroll
            for (int ni = 0; ni < 4; ++ni) {
                const int cl = wn * 64 + ni * 16 + l16;
                const float bv = bias[colBlk + cl];
#pragma unroll
                for (int mi = 0; mi < 4; ++mi)
#pragma unroll
                    for (int r = 0; r < 4; ++r) {
                        int rl = mi * 16 + quad * 4 + r;   // 0..63 within half
                        Ep[rl * 132 + cl] = acc[mi][ni][r] + bv;
                    }
            }
        }
        __syncthreads();
        {
            const int r0 = tid >> 5;          // 0..7
            const int c4 = (tid & 31) * 4;    // 0..124
#pragma unroll
            for (int j = 0; j < 8; ++j) {
                int rl = j * 8 + r0;
                f32x4 v = *(const f32x4*)(Ep + rl * 132 + c4);
                *(f32x4*)(out + (size_t)(rowBlk + h * 64 + rl) * CH + colBlk + c4) = v;
            }
        }
        __syncthreads();   // readers done before next half's staging overwrites Ep
    }
}

extern "C" void kernel_launch(void* const* d_in, const int* in_sizes, int n_in,
                              void* d_out, int out_size, void* d_ws, size_t ws_size,
                              hipStream_t stream) {
    const float* x      = (const float*)d_in[0];
    const float* qkv_w  = (const float*)d_in[1];
    const float* proj_w = (const float*)d_in[2];
    const float* proj_b = (const float*)d_in[3];
    float* out = (float*)d_out;

    char* ws = (char*)d_ws;
    const size_t nX = (size_t)B_SZ * SEQ * CH;
    const size_t nW = (size_t)3 * CH * CH;
    const size_t nP = (size_t)CH * CH;
    const size_t nQ = (size_t)B_SZ * NH * SEQ * HD;

    __bf16* Xb = (__bf16*)(ws);
    __bf16* Wb = (__bf16*)(ws + 2 * nX);
    __bf16* Pw = (__bf16*)(ws + 2 * (nX + nW));
    __bf16* Qb = (__bf16*)(ws + 2 * (nX + nW + nP));
    __bf16* Kb = (__bf16*)(ws + 2 * (nX + nW + nP + nQ));
    __bf16* Vt = (__bf16*)(ws + 2 * (nX + nW + nP + 2 * nQ));
    __bf16* Ab = (__bf16*)(ws + 2 * (nX + nW + nP + 3 * nQ));

    convert_all<<<NBLK_X + NBLK_W + NBLK_P, 256, 0, stream>>>(x, qkv_w, proj_w, Xb, Wb, Pw);

    qkv_gemm<<<1152, 256, 0, stream>>>(Xb, Wb, Qb, Kb, Vt);

    flash_attn<<<768, 256, 0, stream>>>(Qb, Kb, Vt, Ab);

    proj_gemm<<<384, 256, 0, stream>>>(Ab, Pw, proj_b, out);
}

// Round 10
// 211.107 us; speedup vs baseline: 1.0073x; 1.0073x over previous
//
#include <hip/hip_runtime.h>

#define B_SZ 4
#define SEQ  2048
#define CH   768
#define NH   12
#define HD   64

typedef float f32x4  __attribute__((ext_vector_type(4)));
typedef __bf16 bf16x8 __attribute__((ext_vector_type(8)));
typedef __bf16 bf16x2 __attribute__((ext_vector_type(2)));
typedef unsigned u32x2 __attribute__((ext_vector_type(2)));

#define MFMA16(a,b,c) __builtin_amdgcn_mfma_f32_16x16x32_bf16(a,b,c,0,0,0)

// scale = 1/sqrt(64) * log2(e)  -> softmax uses exp2
#define QSCALE 0.1803368801111204f

#if __has_builtin(__builtin_amdgcn_exp2f)
#define EXP2(x) __builtin_amdgcn_exp2f(x)
#else
#define EXP2(x) exp2f(x)
#endif

// flash LDS swizzle
#define SWZ(row) (((row) ^ ((row) >> 3)) & 7)

__device__ __forceinline__ unsigned pack2(float a, float b) {
    union { bf16x2 v; unsigned u; } p;
    p.v[0] = (__bf16)a; p.v[1] = (__bf16)b;
    return p.u;
}

// lane i <-> i^16 exchange. R9's inline-asm version NaN'd: both "+v" operands coalesced to ONE
// physical register, so the instruction's two result writes conflicted. The intrinsic returns
// two distinct SSA values -> backend guarantees distinct registers. With both inputs = x:
// r[0]=[r0,r0,r2,r2] (vdst side), r[1]=[r1,r1,r3,r3] (vsrc side); quad&1 ? r[0] : r[1] ==
// shfl_xor(x,16) exactly. Fallback reproduces the proven shfl path.
#if __has_builtin(__builtin_amdgcn_permlane16_swap)
#define HAVE_PLS16 1
#else
#define HAVE_PLS16 0
#endif

// async global->LDS, 16B per lane. lds dest must be wave-uniform base + lane*16.
__device__ __forceinline__ void lds_dma16(const void* g, void* l) {
    __builtin_amdgcn_global_load_lds(
        (const __attribute__((address_space(1))) void*)g,
        (__attribute__((address_space(3))) void*)(unsigned)(unsigned long long)l,
        16, 0, 0);
}

// ---------------- fused fp32 -> bf16 convert (x | qkv_w | proj_w in one launch) ------------
#define NBLK_X  6144   // 6291456 / 1024
#define NBLK_W  1728   // 1769472 / 1024
#define NBLK_P   576   //  589824 / 1024
__global__ __launch_bounds__(256) void convert_all(const float* __restrict__ x,
                                                   const float* __restrict__ w,
                                                   const float* __restrict__ p,
                                                   __bf16* __restrict__ ox,
                                                   __bf16* __restrict__ ow,
                                                   __bf16* __restrict__ op) {
    int blk = blockIdx.x;
    const float* src;
    __bf16* dst;
    int base;
    if (blk < NBLK_X)               { src = x; dst = ox; base = blk; }
    else if (blk < NBLK_X + NBLK_W) { src = w; dst = ow; base = blk - NBLK_X; }
    else                            { src = p; dst = op; base = blk - NBLK_X - NBLK_W; }
    int i = (base * 256 + threadIdx.x) * 4;
    float4 v = *(const float4*)(src + i);
    union { __bf16 h[4]; uint2 u; } o;
    o.h[0] = (__bf16)v.x; o.h[1] = (__bf16)v.y; o.h[2] = (__bf16)v.z; o.h[3] = (__bf16)v.w;
    *(uint2*)(dst + i) = o.u;
}

// ---------------- 128x128 tile (BK=64) MFMA mainloop: C = A(MxK) * B(NxK)^T ----------------
// LDS layout: row-major [128][64] bf16, 16B chunk c stored at phys chunk c ^ (row&7).
__device__ __forceinline__ void gemm128_loop(const __bf16* __restrict__ A,
                                             const __bf16* __restrict__ Bm,
                                             int K, int rowBlk, int colBlk,
                                             __bf16* As, __bf16* Bs,
                                             f32x4 acc[4][4]) {
    const int tid  = threadIdx.x;
    const int lane = tid & 63, wid = tid >> 6;
    const int quad = lane >> 4, l16 = lane & 15;
    const int wm = wid >> 1, wn = wid & 1;

    f32x4 z = {0.f, 0.f, 0.f, 0.f};
#pragma unroll
    for (int mi = 0; mi < 4; ++mi)
#pragma unroll
        for (int ni = 0; ni < 4; ++ni) acc[mi][ni] = z;

    for (int k0 = 0; k0 < K; k0 += 64) {
        __syncthreads();
#pragma unroll
        for (int i = 0; i < 4; ++i) {
            int s = i * 256 + tid;
            int row = s >> 3, pc = s & 7;
            int lc = pc ^ (row & 7);
            lds_dma16(A  + (size_t)(rowBlk + row) * K + k0 + lc * 8, As + s * 8);
            lds_dma16(Bm + (size_t)(colBlk + row) * K + k0 + lc * 8, Bs + s * 8);
        }
        __syncthreads();

#pragma unroll
        for (int kc = 0; kc < 2; ++kc) {
            bf16x8 af[4], bfr[4];
#pragma unroll
            for (int mi = 0; mi < 4; ++mi) {
                int row = wm * 64 + mi * 16 + l16;
                int pc = (quad + 4 * kc) ^ (row & 7);
                af[mi] = *(const bf16x8*)(As + row * 64 + pc * 8);
            }
#pragma unroll
            for (int ni = 0; ni < 4; ++ni) {
                int row = wn * 64 + ni * 16 + l16;
                int pc = (quad + 4 * kc) ^ (row & 7);
                bfr[ni] = *(const bf16x8*)(Bs + row * 64 + pc * 8);
            }
#pragma unroll
            for (int mi = 0; mi < 4; ++mi)
#pragma unroll
                for (int ni = 0; ni < 4; ++ni)
                    acc[mi][ni] = MFMA16(af[mi], bfr[ni], acc[mi][ni]);
        }
    }
}

// ---------------- QKV GEMM: X(8192x768) @ Wqkv(2304x768)^T, scatter to Q/K/Vt ----------------
// R7 epilogue (kept): Q/K vectorized via LDS transpose; 2D grid (R8's XCD chunking was neutral).
__global__ __launch_bounds__(256) void qkv_gemm(const __bf16* __restrict__ Xb,
                                                const __bf16* __restrict__ Wb,
                                                __bf16* __restrict__ Qb,
                                                __bf16* __restrict__ Kb,
                                                __bf16* __restrict__ Vt) {
    __shared__ __bf16 smem[128 * 128];   // 32 KB: mainloop uses first 16 KB; epilogue all
    f32x4 acc[4][4];
    const int rowBlk = blockIdx.x * 128, colBlk = blockIdx.y * 128;
    gemm128_loop(Xb, Wb, CH, rowBlk, colBlk, smem, smem + 128 * 64, acc);

    const int tid = threadIdx.x;
    const int lane = tid & 63, wid = tid >> 6;
    const int quad = lane >> 4, l16 = lane & 15, wm = wid >> 1, wn = wid & 1;
    const int b = rowBlk >> 11, n0 = rowBlk & (SEQ - 1);

    if (colBlk < 2 * CH) {
        const int isK = (colBlk >= CH);
        const float sc = isK ? 1.f : QSCALE;
        const int hb = (colBlk - (isK ? CH : 0)) >> 6;   // base head of this 128-col block
        __syncthreads();   // mainloop LDS readers done; reuse as [128][128]
#pragma unroll
        for (int mi = 0; mi < 4; ++mi)
#pragma unroll
            for (int ni = 0; ni < 4; ++ni)
#pragma unroll
                for (int r = 0; r < 4; ++r) {
                    int rl = wm * 64 + mi * 16 + quad * 4 + r;   // n-local
                    int cl = wn * 64 + ni * 16 + l16;            // col-local (2 heads x 64 d)
                    smem[rl * 128 + (cl ^ ((rl & 15) << 3))] = (__bf16)(acc[mi][ni][r] * sc);
                }
        __syncthreads();
        __bf16* dst0 = isK ? Kb : Qb;
        const int rbase = tid >> 4;          // 0..15
        const int c = (tid & 15) * 8;        // 0..120, 8-aligned
        const int h = hb + (c >> 6), d = c & 63;
#pragma unroll
        for (int j = 0; j < 8; ++j) {
            int rl = j * 16 + rbase;
            uint4 val = *(const uint4*)(smem + rl * 128 + (c ^ ((rl & 15) << 3)));
            *(uint4*)(dst0 + (size_t)((b * NH + h) * SEQ + n0 + rl) * HD + d) = val;
        }
    } else {
        // V: transpose through LDS, write V^T coalesced
        const int vblk = colBlk - 2 * CH;
        __syncthreads();
#pragma unroll
        for (int mi = 0; mi < 4; ++mi)
#pragma unroll
            for (int ni = 0; ni < 4; ++ni)
#pragma unroll
                for (int r = 0; r < 4; ++r) {
                    int rl = wm * 64 + mi * 16 + quad * 4 + r;   // n-local
                    int cl = wn * 64 + ni * 16 + l16;            // d-local
                    smem[cl * 128 + (((rl >> 3) ^ (cl & 15)) << 3) + (rl & 7)] =
                        (__bf16)acc[mi][ni][r];
                }
        __syncthreads();
        const int dl = tid >> 1;
        const int d  = vblk + dl;
        const int h  = d >> 6, dd = d & 63;
        const size_t base = (size_t)((b * NH + h) * HD + dd) * SEQ + n0;
#pragma unroll
        for (int j2 = 0; j2 < 8; ++j2) {
            int j = (tid & 1) * 8 + j2;
            uint4 val = *(const uint4*)(smem + dl * 128 + ((j ^ (dl & 15)) << 3));
            *(uint4*)(Vt + base + j * 8) = val;
        }
    }
}

// ---------------- Flash attention v16: R0 structure + permlane16_swap (intrinsic) ------------
// The P-exchange shfl_xor(..,16) is an LDS-pipe op on the serial chain QK->exp->pack->XCHG->PV
// and accounts for most of the 6.44M bank conflicts. gfx950's permlane16_swap does the i<->i^16
// exchange purely in VALU. Intrinsic (not asm) so the two results get distinct registers.
__global__ __launch_bounds__(256, 3) void flash_attn(const __bf16* __restrict__ Qb,
                                                     const __bf16* __restrict__ Kb,
                                                     const __bf16* __restrict__ Vt,
                                                     __bf16* __restrict__ Ab) {
    __shared__ __bf16 smem[16384];       // 32 KB: Ks0|Vs0|Ks1|Vs1 (4KB elements each)
                                         // epilogue reuses first 18 KB as [128][72]

    const int tid  = threadIdx.x;
    const int lane = tid & 63, wid = tid >> 6;
    const int quad = lane >> 4, l16 = lane & 15;

    // XCD-aware decode: blk%8 = XCD; 6 bh x 16 qblk per XCD.
    const int lin  = blockIdx.x;              // 0..767
    const int xcd  = lin & 7, idx = lin >> 3; // idx 0..95
    const int bh   = xcd * 6 + (idx >> 4);    // 0..47
    const int qblk = idx & 15;                // 0..15 (128 queries each)
    const int b    = bh / NH, head = bh - b * NH;

    const int qA = qblk * 128 + wid * 16 + l16;
    const int qB = qA + 64;

    // Q^T B-frags (held whole kernel): lane n=l16=q, k(d) = kcd*32 + quad*8 + j
    bf16x8 qfA[2], qfB[2];
#pragma unroll
    for (int kcd = 0; kcd < 2; ++kcd) {
        qfA[kcd] = *(const bf16x8*)(Qb + (size_t)(bh * SEQ + qA) * HD + kcd * 32 + quad * 8);
        qfB[kcd] = *(const bf16x8*)(Qb + (size_t)(bh * SEQ + qB) * HD + kcd * 32 + quad * 8);
    }

    // key permutation (even/odd groups) for zero-cndmask P exchange
    const int key_e = ((l16 >> 2) << 3) + (l16 & 3);
    const int key_o = ((((l16 >> 2) ^ 1)) << 3) + 4 + (l16 & 3);

    f32x4 otA[4], otB[4];
    f32x4 z = {0.f, 0.f, 0.f, 0.f};
#pragma unroll
    for (int dg = 0; dg < 4; ++dg) { otA[dg] = z; otB[dg] = z; }
    float lA = 0.f, lB = 0.f;

    const __bf16* Kbh = Kb + (size_t)bh * SEQ * HD;
    const __bf16* Vbh = Vt + (size_t)bh * HD * SEQ;

    const int s_row = tid >> 3, s_pc = tid & 7;
    const int s_lc0 = s_pc ^ SWZ(s_row);
    const int s_lc1 = s_pc ^ SWZ(s_row + 32);

#if HAVE_PLS16
#define XCHG16(x, out)                                                          \
    do {                                                                        \
        u32x2 r_ = __builtin_amdgcn_permlane16_swap((x), (x), false, false);    \
        out = (quad & 1) ? r_[0] : r_[1];                                       \
    } while (0)
#else
#define XCHG16(x, out)                                                          \
    do { out = (unsigned)__shfl_xor((int)(x), 16, 64); } while (0)
#endif

// proven R8 64-key body on sub-tile at (Ks, Vs); P-exchange via permlane intrinsic
#define PROCESS(Ks, Vs)                                                                       \
    do {                                                                                      \
        f32x4 stA[4], stB[4];                                                                 \
        _Pragma("unroll")                                                                     \
        for (int g = 0; g < 4; ++g) { stA[g] = z; stB[g] = z; }                               \
        _Pragma("unroll")                                                                     \
        for (int g = 0; g < 4; ++g) {                                                         \
            const int key = ((g >> 1) << 5) + ((g & 1) ? key_o : key_e);                      \
            _Pragma("unroll")                                                                 \
            for (int kcd = 0; kcd < 2; ++kcd) {                                               \
                int c8 = quad + (kcd << 2);                                                   \
                bf16x8 kf = *(const bf16x8*)((Ks) + key * 64 + ((c8 ^ SWZ(key)) << 3));       \
                stA[g] = MFMA16(kf, qfA[kcd], stA[g]);                                        \
                stB[g] = MFMA16(kf, qfB[kcd], stB[g]);                                        \
            }                                                                                 \
        }                                                                                     \
        bf16x8 pfA[2], pfB[2];                                                                \
        _Pragma("unroll")                                                                     \
        for (int g = 0; g < 4; ++g)                                                           \
            _Pragma("unroll")                                                                 \
            for (int r = 0; r < 4; ++r) {                                                     \
                float p = EXP2(stA[g][r]);                                                    \
                stA[g][r] = p;                                                                \
                lA += p;                                                                      \
            }                                                                                 \
        _Pragma("unroll")                                                                     \
        for (int kk = 0; kk < 2; ++kk) {                                                      \
            unsigned w0 = pack2(stA[2 * kk][0], stA[2 * kk][1]);                              \
            unsigned w1 = pack2(stA[2 * kk][2], stA[2 * kk][3]);                              \
            unsigned x0 = pack2(stA[2 * kk + 1][0], stA[2 * kk + 1][1]);                      \
            unsigned x1 = pack2(stA[2 * kk + 1][2], stA[2 * kk + 1][3]);                      \
            unsigned w2, w3;                                                                  \
            XCHG16(x0, w2);                                                                   \
            XCHG16(x1, w3);                                                                   \
            union { bf16x8 v; unsigned u[4]; } f;                                             \
            f.u[0] = w0; f.u[1] = w1; f.u[2] = w2; f.u[3] = w3;                               \
            pfA[kk] = f.v;                                                                    \
        }                                                                                     \
        _Pragma("unroll")                                                                     \
        for (int g = 0; g < 4; ++g)                                                           \
            _Pragma("unroll")                                                                 \
            for (int r = 0; r < 4; ++r) {                                                     \
                float p = EXP2(stB[g][r]);                                                    \
                stB[g][r] = p;                                                                \
                lB += p;                                                                      \
            }                                                                                 \
        _Pragma("unroll")                                                                     \
        for (int kk = 0; kk < 2; ++kk) {                                                      \
            unsigned w0 = pack2(stB[2 * kk][0], stB[2 * kk][1]);                              \
            unsigned w1 = pack2(stB[2 * kk][2], stB[2 * kk][3]);                              \
            unsigned x0 = pack2(stB[2 * kk + 1][0], stB[2 * kk + 1][1]);                      \
            unsigned x1 = pack2(stB[2 * kk + 1][2], stB[2 * kk + 1][3]);                      \
            unsigned w2, w3;                                                                  \
            XCHG16(x0, w2);                                                                   \
            XCHG16(x1, w3);                                                                   \
            union { bf16x8 v; unsigned u[4]; } f;                                             \
            f.u[0] = w0; f.u[1] = w1; f.u[2] = w2; f.u[3] = w3;                               \
            pfB[kk] = f.v;                                                                    \
        }                                                                                     \
        _Pragma("unroll")                                                                     \
        for (int dg = 0; dg < 4; ++dg)                                                        \
            _Pragma("unroll")                                                                 \
            for (int kk = 0; kk < 2; ++kk) {                                                  \
                int row = (dg << 4) + l16;                                                    \
                int c8 = quad + (kk << 2);                                                    \
                bf16x8 vf = *(const bf16x8*)((Vs) + row * 64 + ((c8 ^ SWZ(row)) << 3));       \
                otA[dg] = MFMA16(vf, pfA[kk], otA[dg]);                                       \
                otB[dg] = MFMA16(vf, pfB[kk], otB[dg]);                                       \
            }                                                                                 \
    } while (0)

    for (int kb = 0; kb < SEQ / 128; ++kb) {
        const int kbase = kb * 128;
        __syncthreads();   // prior-iteration LDS readers done
        // sub-tile 0: keys kbase..kbase+63
        lds_dma16(Kbh + (size_t)(kbase + s_row) * HD + s_lc0 * 8,            smem + tid * 8);
        lds_dma16(Kbh + (size_t)(kbase + s_row + 32) * HD + s_lc1 * 8,       smem + 2048 + tid * 8);
        lds_dma16(Vbh + (size_t)s_row * SEQ + kbase + s_lc0 * 8,             smem + 4096 + tid * 8);
        lds_dma16(Vbh + (size_t)(s_row + 32) * SEQ + kbase + s_lc1 * 8,      smem + 6144 + tid * 8);
        // sub-tile 1: keys kbase+64..kbase+127
        lds_dma16(Kbh + (size_t)(kbase + 64 + s_row) * HD + s_lc0 * 8,       smem + 8192 + tid * 8);
        lds_dma16(Kbh + (size_t)(kbase + 96 + s_row) * HD + s_lc1 * 8,       smem + 10240 + tid * 8);
        lds_dma16(Vbh + (size_t)s_row * SEQ + kbase + 64 + s_lc0 * 8,        smem + 12288 + tid * 8);
        lds_dma16(Vbh + (size_t)(s_row + 32) * SEQ + kbase + 64 + s_lc1 * 8, smem + 14336 + tid * 8);
        __syncthreads();   // drains dma

        PROCESS(smem, smem + 4096);
        PROCESS(smem + 8192, smem + 12288);
    }
#undef PROCESS

    lA += __shfl_xor(lA, 16, 64);
    lA += __shfl_xor(lA, 32, 64);
    lB += __shfl_xor(lB, 16, 64);
    lB += __shfl_xor(lB, 32, 64);
    const float rA = 1.f / lA, rB = 1.f / lB;

    __syncthreads();   // reuse smem as [128][72] for O transpose
    __bf16 (*Ob)[72] = (__bf16(*)[72])smem;
#pragma unroll
    for (int dg = 0; dg < 4; ++dg)
#pragma unroll
        for (int r = 0; r < 4; ++r) {
            int d = (dg << 4) + (quad << 2) + r;
            Ob[wid * 16 + l16][d]      = (__bf16)(otA[dg][r] * rA);
            Ob[64 + wid * 16 + l16][d] = (__bf16)(otB[dg][r] * rB);
        }
    __syncthreads();
    {
        const int row = tid >> 1, c0 = (tid & 1) * 32;
        __bf16* dst = Ab + (size_t)(b * SEQ + qblk * 128 + row) * CH + head * HD + c0;
#pragma unroll
        for (int j = 0; j < 4; ++j)
            *(uint4*)(dst + j * 8) = *(const uint4*)(&Ob[row][c0 + j * 8]);
    }
}

// ---------------- Projection GEMM: Attn(8192x768) @ proj_w(768x768)^T + bias ----------------
__global__ __launch_bounds__(256) void proj_gemm(const __bf16* __restrict__ Ab,
                                                 const __bf16* __restrict__ Pw,
                                                 const float* __restrict__ bias,
                                                 float* __restrict__ out) {
    __shared__ __bf16 As[128 * 64];
    __shared__ __bf16 Bs[128 * 64];
    f32x4 acc[4][4];
    const int rowBlk = blockIdx.x * 128, colBlk = blockIdx.y * 128;
    gemm128_loop(Ab, Pw, CH, rowBlk, colBlk, As, Bs, acc);

    const int lane = threadIdx.x & 63, wid = threadIdx.x >> 6;
    const int quad = lane >> 4, l16 = lane & 15, wm = wid >> 1, wn = wid & 1;
#pragma unroll
    for (int mi = 0; mi < 4; ++mi)
#pragma unroll
        for (int ni = 0; ni < 4; ++ni)
#pragma unroll
            for (int r = 0; r < 4; ++r) {
                int row = rowBlk + wm * 64 + mi * 16 + quad * 4 + r;
                int col = colBlk + wn * 64 + ni * 16 + l16;
                out[(size_t)row * CH + col] = acc[mi][ni][r] + bias[col];
            }
}

extern "C" void kernel_launch(void* const* d_in, const int* in_sizes, int n_in,
                              void* d_out, int out_size, void* d_ws, size_t ws_size,
                              hipStream_t stream) {
    const float* x      = (const float*)d_in[0];
    const float* qkv_w  = (const float*)d_in[1];
    const float* proj_w = (const float*)d_in[2];
    const float* proj_b = (const float*)d_in[3];
    float* out = (float*)d_out;

    char* ws = (char*)d_ws;
    const size_t nX = (size_t)B_SZ * SEQ * CH;
    const size_t nW = (size_t)3 * CH * CH;
    const size_t nP = (size_t)CH * CH;
    const size_t nQ = (size_t)B_SZ * NH * SEQ * HD;

    __bf16* Xb = (__bf16*)(ws);
    __bf16* Wb = (__bf16*)(ws + 2 * nX);
    __bf16* Pw = (__bf16*)(ws + 2 * (nX + nW));
    __bf16* Qb = (__bf16*)(ws + 2 * (nX + nW + nP));
    __bf16* Kb = (__bf16*)(ws + 2 * (nX + nW + nP + nQ));
    __bf16* Vt = (__bf16*)(ws + 2 * (nX + nW + nP + 2 * nQ));
    __bf16* Ab = (__bf16*)(ws + 2 * (nX + nW + nP + 3 * nQ));

    convert_all<<<NBLK_X + NBLK_W + NBLK_P, 256, 0, stream>>>(x, qkv_w, proj_w, Xb, Wb, Pw);

    qkv_gemm<<<dim3((B_SZ * SEQ) / 128, (3 * CH) / 128), 256, 0, stream>>>(Xb, Wb, Qb, Kb, Vt);

    flash_attn<<<768, 256, 0, stream>>>(Qb, Kb, Vt, Ab);

    proj_gemm<<<dim3((B_SZ * SEQ) / 128, CH / 128), 256, 0, stream>>>(Ab, Pw, proj_b, out);
}